// Round 7
// baseline (244.776 us; speedup 1.0000x reference)
//
#include <hip/hip_runtime.h>
#include <stdint.h>

// B=8, OBJ=128, INP=64, HID=256, D=192.
// pair: out^T = W^T·h^T per (b,i,j-half). Wave tile n=64 x j=64, acc[4][4]
// (->AGPR), af/bfr double-buffered. R6 confirmed: no spills at VGPR=116.
// R7 single-variable change: launch_bounds(256,2) -> (256,4). 4 WGs/CU
// (132 KB LDS, 16 waves/CU) to cover the per-step L2 latency with TLP.

#define HID 256
#define NOBJ 128
#define NROW 1024   // B*OBJ

typedef __attribute__((ext_vector_type(8))) short short8;
typedef __attribute__((ext_vector_type(4))) float float4v;
typedef __attribute__((ext_vector_type(2))) unsigned int uint2v;

__device__ __forceinline__ unsigned int f2bf_u(float f) {
    unsigned int u = __builtin_bit_cast(unsigned int, f);
    u += 0x7fffu + ((u >> 16) & 1u);   // RNE
    return u >> 16;
}
__device__ __forceinline__ unsigned int pack2(float a, float b) {
    return f2bf_u(a) | (f2bf_u(b) << 16);
}
__device__ __forceinline__ float relu(float v) { return v > 0.f ? v : 0.f; }

// LDS-only barrier: leaves global-load (vmcnt) prefetches in flight.
__device__ __forceinline__ void lds_barrier() {
    asm volatile("s_waitcnt lgkmcnt(0)\n\ts_barrier" ::: "memory");
}

// ---- setup: blocks [0,48) coalesced transpose w1..w3 -> bf16 wt[l][n][k];
//             blocks [48,560) encoder (2 rows each, fold b_enc into ea)
__global__ void setup_kernel(const float* __restrict__ x0, const float* __restrict__ x1,
                             const float* __restrict__ x2, const float* __restrict__ w_enc,
                             const float* __restrict__ b_enc,
                             const float* __restrict__ w1, const float* __restrict__ w2,
                             const float* __restrict__ w3,
                             unsigned short* __restrict__ wt,
                             float* __restrict__ ea, float* __restrict__ eb) {
    const int bx = blockIdx.x, t = threadIdx.x;
    __shared__ float tile[64][65];
    __shared__ float xs[2][192];
    if (bx < 48) {
        const int m = bx / 16, tl = bx % 16;
        const int n0 = (tl & 3) * 64, k0 = (tl >> 2) * 64;
        const float* w = (m == 0) ? w1 : (m == 1) ? w2 : w3;
        const int nn = t & 63, kk = t >> 6;
#pragma unroll
        for (int it = 0; it < 16; ++it) {
            int k = kk + it * 4;
            tile[k][nn] = w[(k0 + k) * 256 + n0 + nn];   // coalesced read
        }
        __syncthreads();
        const int k2 = t & 63, nb = t >> 6;
#pragma unroll
        for (int it = 0; it < 16; ++it) {
            int n = nb + it * 4;
            wt[m * 65536 + (n0 + n) * 256 + k0 + k2] =
                (unsigned short)f2bf_u(tile[k2][n]);      // coalesced write
        }
        return;
    }
    const int e = bx - 48;                 // 512 groups x 2 rows
    for (int idx = t; idx < 384; idx += 256) {
        int r = idx / 192, d = idx % 192;
        int row = e * 2 + r;
        float v = (d < 64) ? x0[row * 64 + d]
                : (d < 128) ? x1[row * 64 + d - 64]
                : x2[row * 64 + d - 128];
        xs[r][d] = v;
    }
    __syncthreads();
    float aA[2] = {0.f, 0.f}, aB[2] = {0.f, 0.f};
#pragma unroll 16
    for (int d = 0; d < 192; ++d) {
        float wa = w_enc[d * 256 + t];
        float wb = w_enc[(192 + d) * 256 + t];
#pragma unroll
        for (int r = 0; r < 2; ++r) { aA[r] += xs[r][d] * wa; aB[r] += xs[r][d] * wb; }
    }
    float be = b_enc[t];
#pragma unroll
    for (int r = 0; r < 2; ++r) {
        ea[(e * 2 + r) * 256 + t] = aA[r] + be;
        eb[(e * 2 + r) * 256 + t] = aB[r];
    }
}

// ---- pair MLP: grid 2048 = (b,i) x j-half. 64 j-rows/WG, 32 KB LDS h,
//      swizzle: elem(j,k) at j*256 + ((k>>3 ^ (j&31))<<3) + (k&7).
//      Wave wv owns n-quarter n0 = wv*64; all waves share the j=64 rows.
__global__ __launch_bounds__(256, 4) void pair_kernel(
        const float* __restrict__ ea, const float* __restrict__ eb,
        const unsigned short* __restrict__ wt,
        const float* __restrict__ b1, const float* __restrict__ b2,
        const float* __restrict__ b3, float* __restrict__ pp) {
    __shared__ __align__(16) unsigned short hbuf[64 * 256];   // 32 KB

    const int bx = blockIdx.x;
    const int w = bx >> 1, half = bx & 1, b = w >> 7;
    const int t = threadIdx.x, wv = t >> 6, lane = t & 63;
    const int lo = lane & 15, hi = lane >> 4;
    const int n0 = wv * 64;

    const unsigned short* aptr = wt + (n0 + lo) * 256 + hi * 8;

    short8 af[2][4], bfr[2][4];
    // flat A-pipeline: layer0/kb0 issued before the preamble
#pragma unroll
    for (int nt = 0; nt < 4; ++nt)
        af[0][nt] = *(const short8*)(aptr + nt * 4096);

    // preamble: h0[j][k] = relu(ea[w][k] + eb[b*128+half*64+j][k]); wave fills j=wv*16..+15
    {
        const float4v va = *(const float4v*)(ea + w * 256 + lane * 4);
        const float* ebbase = eb + (b * NOBJ + half * 64) * 256;
        const int c = lane >> 1, sub = (lane & 1) * 4;
#pragma unroll 4
        for (int jj = 0; jj < 16; ++jj) {
            const int j = wv * 16 + jj;
            float4v vb = *(const float4v*)(ebbase + j * 256 + lane * 4);
            int addr = j * 256 + ((c ^ (j & 31)) << 3) + sub;
            *(uint2v*)(hbuf + addr) = (uint2v){
                pack2(relu(va[0] + vb[0]), relu(va[1] + vb[1])),
                pack2(relu(va[2] + vb[2]), relu(va[3] + vb[3]))};
        }
    }
    lds_barrier();

    int jbase[4], jx[4];
#pragma unroll
    for (int jt = 0; jt < 4; ++jt) {
        int jr = jt * 16 + lo;
        jbase[jt] = jr * 256;
        jx[jt] = jr & 31;
    }
    // bfr kb=0 of layer 0
#pragma unroll
    for (int jt = 0; jt < 4; ++jt)
        bfr[0][jt] = *(const short8*)(hbuf + jbase[jt] + ((hi ^ jx[jt]) << 3));

    float4v acc[4][4];   // [nt][jt]

#pragma unroll
    for (int l = 0; l < 3; ++l) {
        const float* bias = (l == 0) ? b1 : (l == 1) ? b2 : b3;
#pragma unroll
        for (int nt = 0; nt < 4; ++nt) {
            float4v bv = *(const float4v*)(bias + n0 + nt * 16 + hi * 4);
#pragma unroll
            for (int jt = 0; jt < 4; ++jt) acc[nt][jt] = bv;
        }
#pragma unroll
        for (int kb = 0; kb < 8; ++kb) {
            const int g = l * 8 + kb, gp = g + 1;
            if (gp < 24) {   // prefetch next step's A (crosses layer boundaries)
                const int lp = gp >> 3, kp = gp & 7;
#pragma unroll
                for (int nt = 0; nt < 4; ++nt)
                    af[gp & 1][nt] = *(const short8*)(aptr + lp * 65536 + nt * 4096 + kp * 32);
            }
            if (kb < 7) {    // prefetch next step's B from LDS
#pragma unroll
                for (int jt = 0; jt < 4; ++jt)
                    bfr[(kb + 1) & 1][jt] = *(const short8*)(hbuf + jbase[jt] +
                        ((((kb + 1) * 4 + hi) ^ jx[jt]) << 3));
            }
#pragma unroll
            for (int nt = 0; nt < 4; ++nt)
#pragma unroll
                for (int jt = 0; jt < 4; ++jt)
                    acc[nt][jt] = __builtin_amdgcn_mfma_f32_16x16x32_bf16(
                        af[g & 1][nt], bfr[kb & 1][jt], acc[nt][jt], 0, 0, 0);
        }
        lds_barrier();   // hbuf reads of layer l done; af prefetch stays in flight

        if (l < 2) {
            // C rows n = n0+nt*16+hi*4+{0..3} (contiguous), cols j = jt*16+lo
#pragma unroll
            for (int nt = 0; nt < 4; ++nt) {
                const int nb_ = n0 + nt * 16 + hi * 4;
                const int cn = nb_ >> 3, sub = nb_ & 7;
#pragma unroll
                for (int jt = 0; jt < 4; ++jt) {
                    float4v v = acc[nt][jt];
                    int j = jt * 16 + lo;
                    int addr = j * 256 + ((cn ^ (j & 31)) << 3) + sub;
                    *(uint2v*)(hbuf + addr) = (uint2v){
                        pack2(relu(v[0]), relu(v[1])),
                        pack2(relu(v[2]), relu(v[3]))};
                }
            }
            lds_barrier();
            // bfr kb=0 of next layer
#pragma unroll
            for (int jt = 0; jt < 4; ++jt)
                bfr[0][jt] = *(const short8*)(hbuf + jbase[jt] + ((hi ^ jx[jt]) << 3));
        } else {
            // partial mean over this WG's 64 j (bias incl. per row; /128 + dec sums halves)
#pragma unroll
            for (int nt = 0; nt < 4; ++nt)
#pragma unroll
                for (int r = 0; r < 4; ++r) {
                    float s = acc[nt][0][r] + acc[nt][1][r] + acc[nt][2][r] + acc[nt][3][r];
                    s += __shfl_xor(s, 1);
                    s += __shfl_xor(s, 2);
                    s += __shfl_xor(s, 4);
                    s += __shfl_xor(s, 8);
                    if (lo == 0)
                        pp[half * (NROW * HID) + w * 256 + n0 + nt * 16 + hi * 4 + r]
                            = s * 0.0078125f;
                }
        }
    }
}

// ---- decoder: 256 WGs x 4 rows. ps = pp_half0 + pp_half1 (= mean + b3).
__global__ void dec_kernel(const float* __restrict__ pp,
                           const float* __restrict__ wd1, const float* __restrict__ bd1,
                           const float* __restrict__ wd2, const float* __restrict__ bd2,
                           float* __restrict__ out) {
    __shared__ float ps[4][256];
    __shared__ float t1[4][260];
    const int g = blockIdx.x, t = threadIdx.x;
#pragma unroll
    for (int r = 0; r < 4; ++r) {
        int row = g * 4 + r;
        ps[r][t] = pp[row * 256 + t] + pp[NROW * HID + row * 256 + t];
    }
    __syncthreads();
    {
        float acc[4];
        float bv = bd1[t];
#pragma unroll
        for (int r = 0; r < 4; ++r) acc[r] = bv;
#pragma unroll 16
        for (int k = 0; k < 256; ++k) {
            float wv = wd1[k * 256 + t];
#pragma unroll
            for (int r = 0; r < 4; ++r) acc[r] += ps[r][k] * wv;
        }
#pragma unroll
        for (int r = 0; r < 4; ++r) t1[r][t] = relu(acc[r]);
    }
    __syncthreads();
    {
        const int o = t & 63, rr = t >> 6;
        float a = 0.f;
#pragma unroll 16
        for (int k = 0; k < 256; ++k) a += t1[rr][k] * wd2[k * 64 + o];
        out[(g * 4 + rr) * 64 + o] = a + bd2[o];
    }
}

extern "C" void kernel_launch(void* const* d_in, const int* in_sizes, int n_in,
                              void* d_out, int out_size, void* d_ws, size_t ws_size,
                              hipStream_t stream) {
    const float* x0    = (const float*)d_in[0];
    const float* x1    = (const float*)d_in[1];
    const float* x2    = (const float*)d_in[2];
    const float* w_enc = (const float*)d_in[3];
    const float* b_enc = (const float*)d_in[4];
    const float* w1    = (const float*)d_in[5];
    const float* b1    = (const float*)d_in[6];
    const float* w2    = (const float*)d_in[7];
    const float* b2    = (const float*)d_in[8];
    const float* w3    = (const float*)d_in[9];
    const float* b3    = (const float*)d_in[10];
    const float* wd1   = (const float*)d_in[11];
    const float* bd1   = (const float*)d_in[12];
    const float* wd2   = (const float*)d_in[13];
    const float* bd2   = (const float*)d_in[14];
    float* out = (float*)d_out;

    // workspace: wt (384KB) | ea (1MB) | eb (1MB) | pp (2MB, two j-halves)
    unsigned short* wt = (unsigned short*)d_ws;
    float* ea = (float*)((char*)d_ws + 3 * 65536 * sizeof(unsigned short));
    float* eb = ea + NROW * HID;
    float* pp = eb + NROW * HID;

    setup_kernel<<<560, 256, 0, stream>>>(x0, x1, x2, w_enc, b_enc, w1, w2, w3, wt, ea, eb);
    pair_kernel<<<2048, 256, 0, stream>>>(ea, eb, wt, b1, b2, b3, pp);
    dec_kernel<<<256, 256, 0, stream>>>(pp, wd1, bd1, wd2, bd2, out);
}

// Round 8
// 233.598 us; speedup vs baseline: 1.0478x; 1.0478x over previous
//
#include <hip/hip_runtime.h>
#include <stdint.h>

// B=8, OBJ=128, INP=64, HID=256, D=192.
// pair: out^T = W^T·h^T per (b,i,j-half). Wave tile n=64 x j=64 as 2x2 tiles
// of 32x32x16 MFMA: acc 64 AGPR (same as 16x16 variant) but af/bfr operand
// buffers halve to 32 VGPR total -> ~120 unified regs, fits 4 waves/SIMD
// (128-reg budget) WITHOUT the spills that killed R7's (256,4) attempt.

#define HID 256
#define NOBJ 128
#define NROW 1024   // B*OBJ

typedef __attribute__((ext_vector_type(8))) short short8;
typedef __attribute__((ext_vector_type(4))) float float4v;
typedef __attribute__((ext_vector_type(16))) float float16v;
typedef __attribute__((ext_vector_type(2))) unsigned int uint2v;

__device__ __forceinline__ unsigned int f2bf_u(float f) {
    unsigned int u = __builtin_bit_cast(unsigned int, f);
    u += 0x7fffu + ((u >> 16) & 1u);   // RNE
    return u >> 16;
}
__device__ __forceinline__ unsigned int pack2(float a, float b) {
    return f2bf_u(a) | (f2bf_u(b) << 16);
}
__device__ __forceinline__ float relu(float v) { return v > 0.f ? v : 0.f; }

// LDS-only barrier: leaves global-load (vmcnt) prefetches in flight.
__device__ __forceinline__ void lds_barrier() {
    asm volatile("s_waitcnt lgkmcnt(0)\n\ts_barrier" ::: "memory");
}

// ---- setup: blocks [0,48) coalesced transpose w1..w3 -> bf16 wt[l][n][k];
//             blocks [48,560) encoder (2 rows each, fold b_enc into ea)
__global__ void setup_kernel(const float* __restrict__ x0, const float* __restrict__ x1,
                             const float* __restrict__ x2, const float* __restrict__ w_enc,
                             const float* __restrict__ b_enc,
                             const float* __restrict__ w1, const float* __restrict__ w2,
                             const float* __restrict__ w3,
                             unsigned short* __restrict__ wt,
                             float* __restrict__ ea, float* __restrict__ eb) {
    const int bx = blockIdx.x, t = threadIdx.x;
    __shared__ float tile[64][65];
    __shared__ float xs[2][192];
    if (bx < 48) {
        const int m = bx / 16, tl = bx % 16;
        const int n0 = (tl & 3) * 64, k0 = (tl >> 2) * 64;
        const float* w = (m == 0) ? w1 : (m == 1) ? w2 : w3;
        const int nn = t & 63, kk = t >> 6;
#pragma unroll
        for (int it = 0; it < 16; ++it) {
            int k = kk + it * 4;
            tile[k][nn] = w[(k0 + k) * 256 + n0 + nn];   // coalesced read
        }
        __syncthreads();
        const int k2 = t & 63, nb = t >> 6;
#pragma unroll
        for (int it = 0; it < 16; ++it) {
            int n = nb + it * 4;
            wt[m * 65536 + (n0 + n) * 256 + k0 + k2] =
                (unsigned short)f2bf_u(tile[k2][n]);      // coalesced write
        }
        return;
    }
    const int e = bx - 48;                 // 512 groups x 2 rows
    for (int idx = t; idx < 384; idx += 256) {
        int r = idx / 192, d = idx % 192;
        int row = e * 2 + r;
        float v = (d < 64) ? x0[row * 64 + d]
                : (d < 128) ? x1[row * 64 + d - 64]
                : x2[row * 64 + d - 128];
        xs[r][d] = v;
    }
    __syncthreads();
    float aA[2] = {0.f, 0.f}, aB[2] = {0.f, 0.f};
#pragma unroll 16
    for (int d = 0; d < 192; ++d) {
        float wa = w_enc[d * 256 + t];
        float wb = w_enc[(192 + d) * 256 + t];
#pragma unroll
        for (int r = 0; r < 2; ++r) { aA[r] += xs[r][d] * wa; aB[r] += xs[r][d] * wb; }
    }
    float be = b_enc[t];
#pragma unroll
    for (int r = 0; r < 2; ++r) {
        ea[(e * 2 + r) * 256 + t] = aA[r] + be;
        eb[(e * 2 + r) * 256 + t] = aB[r];
    }
}

// ---- pair MLP: grid 2048 = (b,i) x j-half. 64 j-rows/WG, 32 KB LDS h,
//      swizzle: elem(j,k) at j*256 + ((k>>3 ^ (j&31))<<3) + (k&7).
//      Wave wv owns n-quarter n0 = wv*64, as 2x2 tiles of 32x32x16 MFMA.
//      A-frag: m=lane&31 (n-row), k=(lane>>5)*8+e. B-frag: col j=lane&31,
//      k=(lane>>5)*8+e. C/D: col j=lane&31, row n=(r&3)+8(r>>2)+4(lane>>5).
__global__ __launch_bounds__(256, 4) void pair_kernel(
        const float* __restrict__ ea, const float* __restrict__ eb,
        const unsigned short* __restrict__ wt,
        const float* __restrict__ b1, const float* __restrict__ b2,
        const float* __restrict__ b3, float* __restrict__ pp) {
    __shared__ __align__(16) unsigned short hbuf[64 * 256];   // 32 KB

    const int bx = blockIdx.x;
    const int w = bx >> 1, half = bx & 1, b = w >> 7;
    const int t = threadIdx.x, wv = t >> 6, lane = t & 63;
    const int l31 = lane & 31, h5 = lane >> 5;
    const int n0 = wv * 64;

    const unsigned short* aptr = wt + (n0 + l31) * 256 + h5 * 8;

    short8 af[2][2], bfr[2][2];
    // flat A-pipeline: layer0/kb0 issued before the preamble
    af[0][0] = *(const short8*)(aptr);
    af[0][1] = *(const short8*)(aptr + 8192);

    // preamble: h0[j][k] = relu(ea[w][k] + eb[b*128+half*64+j][k]); wave fills j=wv*16..+15
    {
        const float4v va = *(const float4v*)(ea + w * 256 + lane * 4);
        const float* ebbase = eb + (b * NOBJ + half * 64) * 256;
        const int c = lane >> 1, sub = (lane & 1) * 4;
#pragma unroll 4
        for (int jj = 0; jj < 16; ++jj) {
            const int j = wv * 16 + jj;
            float4v vb = *(const float4v*)(ebbase + j * 256 + lane * 4);
            int addr = j * 256 + ((c ^ (j & 31)) << 3) + sub;
            *(uint2v*)(hbuf + addr) = (uint2v){
                pack2(relu(va[0] + vb[0]), relu(va[1] + vb[1])),
                pack2(relu(va[2] + vb[2]), relu(va[3] + vb[3]))};
        }
    }
    lds_barrier();

    const int jb0 = l31 * 256, jb1 = (32 + l31) * 256;
    // bfr kb=0 of layer 0: k-chunk ck = h5
    bfr[0][0] = *(const short8*)(hbuf + jb0 + ((h5 ^ l31) << 3));
    bfr[0][1] = *(const short8*)(hbuf + jb1 + ((h5 ^ l31) << 3));

    float16v acc[2][2];   // [tn][tj]

#pragma unroll
    for (int l = 0; l < 3; ++l) {
        const float* bias = (l == 0) ? b1 : (l == 1) ? b2 : b3;
        // acc init: reg r of tile tn -> n = n0+tn*32 + (r&3)+8*(r>>2)+4*h5
#pragma unroll
        for (int tn = 0; tn < 2; ++tn)
#pragma unroll
            for (int q = 0; q < 4; ++q) {
                float4v bv = *(const float4v*)(bias + n0 + tn * 32 + q * 8 + h5 * 4);
#pragma unroll
                for (int i = 0; i < 4; ++i) {
                    acc[tn][0][q * 4 + i] = bv[i];
                    acc[tn][1][q * 4 + i] = bv[i];
                }
            }
#pragma unroll
        for (int kb = 0; kb < 16; ++kb) {
            const int g = l * 16 + kb, gp = g + 1;
            if (gp < 48) {   // prefetch next step's A (crosses layer boundaries)
                const int lp = gp >> 4, kp = gp & 15;
                af[gp & 1][0] = *(const short8*)(aptr + lp * 65536 + kp * 16);
                af[gp & 1][1] = *(const short8*)(aptr + lp * 65536 + 8192 + kp * 16);
            }
            if (kb < 15) {   // prefetch next step's B from LDS (k-chunk ck=(kb+1)*2+h5)
                const int off = ((((kb + 1) * 2 + h5) ^ l31) << 3);
                bfr[(kb + 1) & 1][0] = *(const short8*)(hbuf + jb0 + off);
                bfr[(kb + 1) & 1][1] = *(const short8*)(hbuf + jb1 + off);
            }
#pragma unroll
            for (int tn = 0; tn < 2; ++tn)
#pragma unroll
                for (int tj = 0; tj < 2; ++tj)
                    acc[tn][tj] = __builtin_amdgcn_mfma_f32_32x32x16_bf16(
                        af[g & 1][tn], bfr[kb & 1][tj], acc[tn][tj], 0, 0, 0);
        }
        lds_barrier();   // hbuf reads of layer l done; af prefetch stays in flight

        if (l < 2) {
            // writeback: quad q of tile (tn,tj): n_base = n0+tn*32+8q+4h5 (4 consecutive n),
            // j = tj*32 + l31; packed 8B into swizzled h layout.
#pragma unroll
            for (int tn = 0; tn < 2; ++tn)
#pragma unroll
                for (int q = 0; q < 4; ++q) {
                    const int nb_ = n0 + tn * 32 + 8 * q + 4 * h5;
                    const int cn = nb_ >> 3, sub = nb_ & 7;
#pragma unroll
                    for (int tj = 0; tj < 2; ++tj) {
                        const int j = tj * 32 + l31;
                        int addr = j * 256 + ((cn ^ l31) << 3) + sub;
                        *(uint2v*)(hbuf + addr) = (uint2v){
                            pack2(relu(acc[tn][tj][q * 4]), relu(acc[tn][tj][q * 4 + 1])),
                            pack2(relu(acc[tn][tj][q * 4 + 2]), relu(acc[tn][tj][q * 4 + 3]))};
                    }
                }
            lds_barrier();
            // bfr kb=0 of next layer
            bfr[0][0] = *(const short8*)(hbuf + jb0 + ((h5 ^ l31) << 3));
            bfr[0][1] = *(const short8*)(hbuf + jb1 + ((h5 ^ l31) << 3));
        } else {
            // partial mean over this WG's 64 j: sum 2 tj-tiles, reduce over 32 j-lanes
#pragma unroll
            for (int tn = 0; tn < 2; ++tn)
#pragma unroll
                for (int r = 0; r < 16; ++r) {
                    float s = acc[tn][0][r] + acc[tn][1][r];
                    s += __shfl_xor(s, 1);
                    s += __shfl_xor(s, 2);
                    s += __shfl_xor(s, 4);
                    s += __shfl_xor(s, 8);
                    s += __shfl_xor(s, 16);
                    if (l31 == 0) {
                        const int n = n0 + tn * 32 + (r & 3) + 8 * (r >> 2) + 4 * h5;
                        pp[half * (NROW * HID) + w * 256 + n] = s * 0.0078125f;
                    }
                }
        }
    }
}

// ---- decoder: 256 WGs x 4 rows. ps = pp_half0 + pp_half1 (= mean + b3).
__global__ void dec_kernel(const float* __restrict__ pp,
                           const float* __restrict__ wd1, const float* __restrict__ bd1,
                           const float* __restrict__ wd2, const float* __restrict__ bd2,
                           float* __restrict__ out) {
    __shared__ float ps[4][256];
    __shared__ float t1[4][260];
    const int g = blockIdx.x, t = threadIdx.x;
#pragma unroll
    for (int r = 0; r < 4; ++r) {
        int row = g * 4 + r;
        ps[r][t] = pp[row * 256 + t] + pp[NROW * HID + row * 256 + t];
    }
    __syncthreads();
    {
        float acc[4];
        float bv = bd1[t];
#pragma unroll
        for (int r = 0; r < 4; ++r) acc[r] = bv;
#pragma unroll 16
        for (int k = 0; k < 256; ++k) {
            float wv = wd1[k * 256 + t];
#pragma unroll
            for (int r = 0; r < 4; ++r) acc[r] += ps[r][k] * wv;
        }
#pragma unroll
        for (int r = 0; r < 4; ++r) t1[r][t] = relu(acc[r]);
    }
    __syncthreads();
    {
        const int o = t & 63, rr = t >> 6;
        float a = 0.f;
#pragma unroll 16
        for (int k = 0; k < 256; ++k) a += t1[rr][k] * wd2[k * 64 + o];
        out[(g * 4 + rr) * 64 + o] = a + bd2[o];
    }
}

extern "C" void kernel_launch(void* const* d_in, const int* in_sizes, int n_in,
                              void* d_out, int out_size, void* d_ws, size_t ws_size,
                              hipStream_t stream) {
    const float* x0    = (const float*)d_in[0];
    const float* x1    = (const float*)d_in[1];
    const float* x2    = (const float*)d_in[2];
    const float* w_enc = (const float*)d_in[3];
    const float* b_enc = (const float*)d_in[4];
    const float* w1    = (const float*)d_in[5];
    const float* b1    = (const float*)d_in[6];
    const float* w2    = (const float*)d_in[7];
    const float* b2    = (const float*)d_in[8];
    const float* w3    = (const float*)d_in[9];
    const float* b3    = (const float*)d_in[10];
    const float* wd1   = (const float*)d_in[11];
    const float* bd1   = (const float*)d_in[12];
    const float* wd2   = (const float*)d_in[13];
    const float* bd2   = (const float*)d_in[14];
    float* out = (float*)d_out;

    // workspace: wt (384KB) | ea (1MB) | eb (1MB) | pp (2MB, two j-halves)
    unsigned short* wt = (unsigned short*)d_ws;
    float* ea = (float*)((char*)d_ws + 3 * 65536 * sizeof(unsigned short));
    float* eb = ea + NROW * HID;
    float* pp = eb + NROW * HID;

    setup_kernel<<<560, 256, 0, stream>>>(x0, x1, x2, w_enc, b_enc, w1, w2, w3, wt, ea, eb);
    pair_kernel<<<2048, 256, 0, stream>>>(ea, eb, wt, b1, b2, b3, pp);
    dec_kernel<<<256, 256, 0, stream>>>(pp, wd1, bd1, wd2, bd2, out);
}

// Round 10
// 197.821 us; speedup vs baseline: 1.2374x; 1.1809x over previous
//
#include <hip/hip_runtime.h>
#include <stdint.h>

// B=8, OBJ=128, INP=64, HID=256, D=192.
// R10 = R9 with the weight-pack indexing bug fixed. Weights stored
// FRAGMENT-MAJOR: wfrag[((l*8+tau)*16+kb)*512 + lane*8+e] = w_l[k][n],
// n = tau*32+(lane&31), k = kb*16+(lane>>5)*8+e. Pair kernel's A-frag load
// is wave-uniform base + lane*16B -> one coalesced 1KB burst (16 sequential
// lines) vs R8's 64-line stride-512B gather (L2 request-rate wall theory).

#define HID 256
#define NOBJ 128
#define NROW 1024   // B*OBJ

typedef __attribute__((ext_vector_type(8))) short short8;
typedef __attribute__((ext_vector_type(4))) float float4v;
typedef __attribute__((ext_vector_type(16))) float float16v;
typedef __attribute__((ext_vector_type(2))) unsigned int uint2v;

__device__ __forceinline__ unsigned int f2bf_u(float f) {
    unsigned int u = __builtin_bit_cast(unsigned int, f);
    u += 0x7fffu + ((u >> 16) & 1u);   // RNE
    return u >> 16;
}
__device__ __forceinline__ unsigned int pack2(float a, float b) {
    return f2bf_u(a) | (f2bf_u(b) << 16);
}
__device__ __forceinline__ float relu(float v) { return v > 0.f ? v : 0.f; }

// LDS-only barrier: leaves global-load (vmcnt) prefetches in flight.
__device__ __forceinline__ void lds_barrier() {
    asm volatile("s_waitcnt lgkmcnt(0)\n\ts_barrier" ::: "memory");
}

// ---- setup: blocks [0,24) fragment-major weight pack: block = (layer m, n-tile tau).
//             blocks [24,536) encoder (2 rows each, fold b_enc into ea)
__global__ void setup_kernel(const float* __restrict__ x0, const float* __restrict__ x1,
                             const float* __restrict__ x2, const float* __restrict__ w_enc,
                             const float* __restrict__ b_enc,
                             const float* __restrict__ w1, const float* __restrict__ w2,
                             const float* __restrict__ w3,
                             unsigned short* __restrict__ wt,
                             float* __restrict__ ea, float* __restrict__ eb) {
    const int bx = blockIdx.x, t = threadIdx.x;
    __shared__ float lw[256][33];          // [k][n-within-tile]
    __shared__ float xs[2][192];
    if (bx < 24) {
        const int m = bx >> 3, tau = bx & 7;
        const float* w = (m == 0) ? w1 : (m == 1) ? w2 : w3;
        const int n = t & 31, kk = t >> 5;     // 8 k-rows per pass
#pragma unroll
        for (int rep = 0; rep < 32; ++rep) {
            int k = rep * 8 + kk;
            lw[k][n] = w[k * 256 + tau * 32 + n];   // coalesced 128B segments
        }
        __syncthreads();
        // pack: each (kb, lane) exactly once. lane = t&63, wave wq owns kb = wq*4..+3.
        unsigned short* outp = wt + (m * 8 + tau) * 8192;
        const int lane = t & 63, wq = t >> 6;
        const int h5 = lane >> 5, l31n = lane & 31;
#pragma unroll
        for (int rep = 0; rep < 4; ++rep) {
            const int kb = wq * 4 + rep;
            short8 v;
#pragma unroll
            for (int e = 0; e < 8; ++e)
                v[e] = (short)f2bf_u(lw[kb * 16 + h5 * 8 + e][l31n]);
            *(short8*)(outp + kb * 512 + lane * 8) = v;   // wave-contiguous 1KB
        }
        return;
    }
    const int e = bx - 24;                 // 512 groups x 2 rows
    for (int idx = t; idx < 384; idx += 256) {
        int r = idx / 192, d = idx % 192;
        int row = e * 2 + r;
        float v = (d < 64) ? x0[row * 64 + d]
                : (d < 128) ? x1[row * 64 + d - 64]
                : x2[row * 64 + d - 128];
        xs[r][d] = v;
    }
    __syncthreads();
    float aA[2] = {0.f, 0.f}, aB[2] = {0.f, 0.f};
#pragma unroll 16
    for (int d = 0; d < 192; ++d) {
        float wa = w_enc[d * 256 + t];
        float wb = w_enc[(192 + d) * 256 + t];
#pragma unroll
        for (int r = 0; r < 2; ++r) { aA[r] += xs[r][d] * wa; aB[r] += xs[r][d] * wb; }
    }
    float be = b_enc[t];
#pragma unroll
    for (int r = 0; r < 2; ++r) {
        ea[(e * 2 + r) * 256 + t] = aA[r] + be;
        eb[(e * 2 + r) * 256 + t] = aB[r];
    }
}

// ---- pair MLP: grid 2048 = (b,i) x j-half. 64 j-rows/WG, 32 KB LDS h,
//      swizzle: elem(j,k) at j*256 + ((k>>3 ^ (j&31))<<3) + (k&7).
//      Wave wv owns n-quarter n0 = wv*64, as 2x2 tiles of 32x32x16 MFMA.
//      A-frag from fragment-major wfrag: coalesced lane*16B burst.
__global__ __launch_bounds__(256, 4) void pair_kernel(
        const float* __restrict__ ea, const float* __restrict__ eb,
        const unsigned short* __restrict__ wt,
        const float* __restrict__ b1, const float* __restrict__ b2,
        const float* __restrict__ b3, float* __restrict__ pp) {
    __shared__ __align__(16) unsigned short hbuf[64 * 256];   // 32 KB

    const int bx = blockIdx.x;
    const int w = bx >> 1, half = bx & 1, b = w >> 7;
    const int t = threadIdx.x, wv = t >> 6, lane = t & 63;
    const int l31 = lane & 31, h5 = lane >> 5;
    const int n0 = wv * 64;

    const unsigned short* aptr = wt + lane * 8;   // + ((l*8 + wv*2+tn)*16 + kb)*512

    short8 af[2][2], bfr[2][2];
    // flat A-pipeline: layer0/kb0 issued before the preamble
    af[0][0] = *(const short8*)(aptr + ((wv * 2 + 0) * 16) * 512);
    af[0][1] = *(const short8*)(aptr + ((wv * 2 + 1) * 16) * 512);

    // preamble: h0[j][k] = relu(ea[w][k] + eb[b*128+half*64+j][k]); wave fills j=wv*16..+15
    {
        const float4v va = *(const float4v*)(ea + w * 256 + lane * 4);
        const float* ebbase = eb + (b * NOBJ + half * 64) * 256;
        const int c = lane >> 1, sub = (lane & 1) * 4;
#pragma unroll 4
        for (int jj = 0; jj < 16; ++jj) {
            const int j = wv * 16 + jj;
            float4v vb = *(const float4v*)(ebbase + j * 256 + lane * 4);
            int addr = j * 256 + ((c ^ (j & 31)) << 3) + sub;
            *(uint2v*)(hbuf + addr) = (uint2v){
                pack2(relu(va[0] + vb[0]), relu(va[1] + vb[1])),
                pack2(relu(va[2] + vb[2]), relu(va[3] + vb[3]))};
        }
    }
    lds_barrier();

    const int jb0 = l31 * 256, jb1 = (32 + l31) * 256;
    // bfr kb=0 of layer 0: k-chunk ck = h5
    bfr[0][0] = *(const short8*)(hbuf + jb0 + ((h5 ^ l31) << 3));
    bfr[0][1] = *(const short8*)(hbuf + jb1 + ((h5 ^ l31) << 3));

    float16v acc[2][2];   // [tn][tj]

#pragma unroll
    for (int l = 0; l < 3; ++l) {
        const float* bias = (l == 0) ? b1 : (l == 1) ? b2 : b3;
        // acc init: reg r of tile tn -> n = n0+tn*32 + (r&3)+8*(r>>2)+4*h5
#pragma unroll
        for (int tn = 0; tn < 2; ++tn)
#pragma unroll
            for (int q = 0; q < 4; ++q) {
                float4v bv = *(const float4v*)(bias + n0 + tn * 32 + q * 8 + h5 * 4);
#pragma unroll
                for (int i = 0; i < 4; ++i) {
                    acc[tn][0][q * 4 + i] = bv[i];
                    acc[tn][1][q * 4 + i] = bv[i];
                }
            }
#pragma unroll
        for (int kb = 0; kb < 16; ++kb) {
            const int g = l * 16 + kb, gp = g + 1;
            if (gp < 48) {   // prefetch next step's A (crosses layer boundaries)
                const int lp = gp >> 4, kp = gp & 15;
                af[gp & 1][0] = *(const short8*)(aptr + ((lp * 8 + wv * 2 + 0) * 16 + kp) * 512);
                af[gp & 1][1] = *(const short8*)(aptr + ((lp * 8 + wv * 2 + 1) * 16 + kp) * 512);
            }
            if (kb < 15) {   // prefetch next step's B from LDS (k-chunk ck=(kb+1)*2+h5)
                const int off = ((((kb + 1) * 2 + h5) ^ l31) << 3);
                bfr[(kb + 1) & 1][0] = *(const short8*)(hbuf + jb0 + off);
                bfr[(kb + 1) & 1][1] = *(const short8*)(hbuf + jb1 + off);
            }
#pragma unroll
            for (int tn = 0; tn < 2; ++tn)
#pragma unroll
                for (int tj = 0; tj < 2; ++tj)
                    acc[tn][tj] = __builtin_amdgcn_mfma_f32_32x32x16_bf16(
                        af[g & 1][tn], bfr[kb & 1][tj], acc[tn][tj], 0, 0, 0);
        }
        lds_barrier();   // hbuf reads of layer l done; af prefetch stays in flight

        if (l < 2) {
            // writeback: quad q of tile (tn,tj): n_base = n0+tn*32+8q+4h5 (4 consecutive n),
            // j = tj*32 + l31; packed 8B into swizzled h layout.
#pragma unroll
            for (int tn = 0; tn < 2; ++tn)
#pragma unroll
                for (int q = 0; q < 4; ++q) {
                    const int nb_ = n0 + tn * 32 + 8 * q + 4 * h5;
                    const int cn = nb_ >> 3, sub = nb_ & 7;
#pragma unroll
                    for (int tj = 0; tj < 2; ++tj) {
                        const int j = tj * 32 + l31;
                        int addr = j * 256 + ((cn ^ l31) << 3) + sub;
                        *(uint2v*)(hbuf + addr) = (uint2v){
                            pack2(relu(acc[tn][tj][q * 4]), relu(acc[tn][tj][q * 4 + 1])),
                            pack2(relu(acc[tn][tj][q * 4 + 2]), relu(acc[tn][tj][q * 4 + 3]))};
                    }
                }
            lds_barrier();
            // bfr kb=0 of next layer
            bfr[0][0] = *(const short8*)(hbuf + jb0 + ((h5 ^ l31) << 3));
            bfr[0][1] = *(const short8*)(hbuf + jb1 + ((h5 ^ l31) << 3));
        } else {
            // partial mean over this WG's 64 j: sum 2 tj-tiles, reduce over 32 j-lanes
#pragma unroll
            for (int tn = 0; tn < 2; ++tn)
#pragma unroll
                for (int r = 0; r < 16; ++r) {
                    float s = acc[tn][0][r] + acc[tn][1][r];
                    s += __shfl_xor(s, 1);
                    s += __shfl_xor(s, 2);
                    s += __shfl_xor(s, 4);
                    s += __shfl_xor(s, 8);
                    s += __shfl_xor(s, 16);
                    if (l31 == 0) {
                        const int n = n0 + tn * 32 + (r & 3) + 8 * (r >> 2) + 4 * h5;
                        pp[half * (NROW * HID) + w * 256 + n] = s * 0.0078125f;
                    }
                }
        }
    }
}

// ---- decoder: 256 WGs x 4 rows. ps = pp_half0 + pp_half1 (= mean + b3).
__global__ void dec_kernel(const float* __restrict__ pp,
                           const float* __restrict__ wd1, const float* __restrict__ bd1,
                           const float* __restrict__ wd2, const float* __restrict__ bd2,
                           float* __restrict__ out) {
    __shared__ float ps[4][256];
    __shared__ float t1[4][260];
    const int g = blockIdx.x, t = threadIdx.x;
#pragma unroll
    for (int r = 0; r < 4; ++r) {
        int row = g * 4 + r;
        ps[r][t] = pp[row * 256 + t] + pp[NROW * HID + row * 256 + t];
    }
    __syncthreads();
    {
        float acc[4];
        float bv = bd1[t];
#pragma unroll
        for (int r = 0; r < 4; ++r) acc[r] = bv;
#pragma unroll 16
        for (int k = 0; k < 256; ++k) {
            float wv = wd1[k * 256 + t];
#pragma unroll
            for (int r = 0; r < 4; ++r) acc[r] += ps[r][k] * wv;
        }
#pragma unroll
        for (int r = 0; r < 4; ++r) t1[r][t] = relu(acc[r]);
    }
    __syncthreads();
    {
        const int o = t & 63, rr = t >> 6;
        float a = 0.f;
#pragma unroll 16
        for (int k = 0; k < 256; ++k) a += t1[rr][k] * wd2[k * 64 + o];
        out[(g * 4 + rr) * 64 + o] = a + bd2[o];
    }
}

extern "C" void kernel_launch(void* const* d_in, const int* in_sizes, int n_in,
                              void* d_out, int out_size, void* d_ws, size_t ws_size,
                              hipStream_t stream) {
    const float* x0    = (const float*)d_in[0];
    const float* x1    = (const float*)d_in[1];
    const float* x2    = (const float*)d_in[2];
    const float* w_enc = (const float*)d_in[3];
    const float* b_enc = (const float*)d_in[4];
    const float* w1    = (const float*)d_in[5];
    const float* b1    = (const float*)d_in[6];
    const float* w2    = (const float*)d_in[7];
    const float* b2    = (const float*)d_in[8];
    const float* w3    = (const float*)d_in[9];
    const float* b3    = (const float*)d_in[10];
    const float* wd1   = (const float*)d_in[11];
    const float* bd1   = (const float*)d_in[12];
    const float* wd2   = (const float*)d_in[13];
    const float* bd2   = (const float*)d_in[14];
    float* out = (float*)d_out;

    // workspace: wfrag (384KB) | ea (1MB) | eb (1MB) | pp (2MB, two j-halves)
    unsigned short* wt = (unsigned short*)d_ws;
    float* ea = (float*)((char*)d_ws + 3 * 65536 * sizeof(unsigned short));
    float* eb = ea + NROW * HID;
    float* pp = eb + NROW * HID;

    setup_kernel<<<536, 256, 0, stream>>>(x0, x1, x2, w_enc, b_enc, w1, w2, w3, wt, ea, eb);
    pair_kernel<<<2048, 256, 0, stream>>>(ea, eb, wt, b1, b2, b3, pp);
    dec_kernel<<<256, 256, 0, stream>>>(pp, wd1, bd1, wd2, bd2, out);
}

// Round 12
// 193.208 us; speedup vs baseline: 1.2669x; 1.0239x over previous
//
#include <hip/hip_runtime.h>
#include <stdint.h>

// B=8, OBJ=128, INP=64, HID=256, D=192.
// R12 = R11 with the packed-bf16 cvt reverted to plain f2bf (bit_cast of
// __hip_bfloat162 doesn't compile). Wave tile n=64 x j=128 (tn=2, tj=4) ->
// 8 MFMAs per k-step per wave (64 cyc issue vs ~150 exposed latency), half
// the af loads per MFMA. One WG per (b,i), 64 KB LDS h, j-mean in-wave.
// Weights fragment-major (R10): af load = wave-uniform base + lane*16B.

#define HID 256
#define NOBJ 128
#define NROW 1024   // B*OBJ

typedef __attribute__((ext_vector_type(8))) short short8;
typedef __attribute__((ext_vector_type(4))) float float4v;
typedef __attribute__((ext_vector_type(16))) float float16v;
typedef __attribute__((ext_vector_type(2))) unsigned int uint2v;

__device__ __forceinline__ unsigned int f2bf_u(float f) {
    unsigned int u = __builtin_bit_cast(unsigned int, f);
    u += 0x7fffu + ((u >> 16) & 1u);   // RNE
    return u >> 16;
}
__device__ __forceinline__ unsigned int pack2(float a, float b) {
    return f2bf_u(a) | (f2bf_u(b) << 16);
}
__device__ __forceinline__ float relu(float v) { return v > 0.f ? v : 0.f; }

// LDS-only barrier: leaves global-load (vmcnt) prefetches in flight.
__device__ __forceinline__ void lds_barrier() {
    asm volatile("s_waitcnt lgkmcnt(0)\n\ts_barrier" ::: "memory");
}

// ---- setup: blocks [0,24) fragment-major weight pack: block = (layer m, n-tile tau).
//             blocks [24,536) encoder (2 rows each, fold b_enc into ea)
__global__ void setup_kernel(const float* __restrict__ x0, const float* __restrict__ x1,
                             const float* __restrict__ x2, const float* __restrict__ w_enc,
                             const float* __restrict__ b_enc,
                             const float* __restrict__ w1, const float* __restrict__ w2,
                             const float* __restrict__ w3,
                             unsigned short* __restrict__ wt,
                             float* __restrict__ ea, float* __restrict__ eb) {
    const int bx = blockIdx.x, t = threadIdx.x;
    __shared__ float lw[256][33];          // [k][n-within-tile]
    __shared__ float xs[2][192];
    if (bx < 24) {
        const int m = bx >> 3, tau = bx & 7;
        const float* w = (m == 0) ? w1 : (m == 1) ? w2 : w3;
        const int n = t & 31, kk = t >> 5;     // 8 k-rows per pass
#pragma unroll
        for (int rep = 0; rep < 32; ++rep) {
            int k = rep * 8 + kk;
            lw[k][n] = w[k * 256 + tau * 32 + n];   // coalesced 128B segments
        }
        __syncthreads();
        // pack: each (kb, lane) exactly once. lane = t&63, wave wq owns kb = wq*4..+3.
        unsigned short* outp = wt + (m * 8 + tau) * 8192;
        const int lane = t & 63, wq = t >> 6;
        const int h5 = lane >> 5, l31n = lane & 31;
#pragma unroll
        for (int rep = 0; rep < 4; ++rep) {
            const int kb = wq * 4 + rep;
            short8 v;
#pragma unroll
            for (int e = 0; e < 8; ++e)
                v[e] = (short)f2bf_u(lw[kb * 16 + h5 * 8 + e][l31n]);
            *(short8*)(outp + kb * 512 + lane * 8) = v;   // wave-contiguous 1KB
        }
        return;
    }
    const int e = bx - 24;                 // 512 groups x 2 rows
    for (int idx = t; idx < 384; idx += 256) {
        int r = idx / 192, d = idx % 192;
        int row = e * 2 + r;
        float v = (d < 64) ? x0[row * 64 + d]
                : (d < 128) ? x1[row * 64 + d - 64]
                : x2[row * 64 + d - 128];
        xs[r][d] = v;
    }
    __syncthreads();
    float aA[2] = {0.f, 0.f}, aB[2] = {0.f, 0.f};
#pragma unroll 16
    for (int d = 0; d < 192; ++d) {
        float wa = w_enc[d * 256 + t];
        float wb = w_enc[(192 + d) * 256 + t];
#pragma unroll
        for (int r = 0; r < 2; ++r) { aA[r] += xs[r][d] * wa; aB[r] += xs[r][d] * wb; }
    }
    float be = b_enc[t];
#pragma unroll
    for (int r = 0; r < 2; ++r) {
        ea[(e * 2 + r) * 256 + t] = aA[r] + be;
        eb[(e * 2 + r) * 256 + t] = aB[r];
    }
}

// ---- pair MLP: grid 1024, one WG per (b,i). 128 j-rows, 64 KB LDS h,
//      swizzle: elem(j,k) at j*256 + ((k>>3 ^ (j&31))<<3) + (k&7).
//      Wave wv owns n-quarter n0 = wv*64 as tn=2 x tj=4 tiles of 32x32x16.
__global__ __launch_bounds__(256, 2) void pair_kernel(
        const float* __restrict__ ea, const float* __restrict__ eb,
        const unsigned short* __restrict__ wt,
        const float* __restrict__ b1, const float* __restrict__ b2,
        const float* __restrict__ b3, float* __restrict__ pooled) {
    __shared__ __align__(16) unsigned short hbuf[128 * 256];   // 64 KB

    const int w = blockIdx.x, b = w >> 7;
    const int t = threadIdx.x, wv = t >> 6, lane = t & 63;
    const int l31 = lane & 31, h5 = lane >> 5;
    const int n0 = wv * 64;

    const unsigned short* aptr = wt + lane * 8;   // + ((l*8 + wv*2+tn)*16 + kb)*512

    short8 af[2][2], bfr[2][4];
    // flat A-pipeline: layer0/kb0 issued before the preamble
    af[0][0] = *(const short8*)(aptr + ((wv * 2 + 0) * 16) * 512);
    af[0][1] = *(const short8*)(aptr + ((wv * 2 + 1) * 16) * 512);

    // preamble: h0[j][k] = relu(ea[w][k] + eb[b*128+j][k]); wave fills j=wv*32..+31
    {
        const float4v va = *(const float4v*)(ea + w * 256 + lane * 4);
        const float* ebbase = eb + (b * NOBJ) * 256;
        const int c = lane >> 1, sub = (lane & 1) * 4;
#pragma unroll 4
        for (int jj = 0; jj < 32; ++jj) {
            const int j = wv * 32 + jj;
            float4v vb = *(const float4v*)(ebbase + j * 256 + lane * 4);
            int addr = j * 256 + ((c ^ (j & 31)) << 3) + sub;
            *(uint2v*)(hbuf + addr) = (uint2v){
                pack2(relu(va[0] + vb[0]), relu(va[1] + vb[1])),
                pack2(relu(va[2] + vb[2]), relu(va[3] + vb[3]))};
        }
    }
    lds_barrier();

    int jb[4];
#pragma unroll
    for (int tj = 0; tj < 4; ++tj) jb[tj] = (tj * 32 + l31) * 256;
    // bfr kb=0 of layer 0: k-chunk ck = h5
#pragma unroll
    for (int tj = 0; tj < 4; ++tj)
        bfr[0][tj] = *(const short8*)(hbuf + jb[tj] + ((h5 ^ l31) << 3));

    float16v acc[2][4];   // [tn][tj]

#pragma unroll
    for (int l = 0; l < 3; ++l) {
        const float* bias = (l == 0) ? b1 : (l == 1) ? b2 : b3;
        // acc init: reg r of tile tn -> n = n0+tn*32 + (r&3)+8*(r>>2)+4*h5
#pragma unroll
        for (int tn = 0; tn < 2; ++tn)
#pragma unroll
            for (int q = 0; q < 4; ++q) {
                float4v bv = *(const float4v*)(bias + n0 + tn * 32 + q * 8 + h5 * 4);
#pragma unroll
                for (int i = 0; i < 4; ++i)
#pragma unroll
                    for (int tj = 0; tj < 4; ++tj)
                        acc[tn][tj][q * 4 + i] = bv[i];
            }
#pragma unroll
        for (int kb = 0; kb < 16; ++kb) {
            const int g = l * 16 + kb, gp = g + 1;
            if (gp < 48) {   // prefetch next step's A (crosses layer boundaries)
                const int lp = gp >> 4, kp = gp & 15;
                af[gp & 1][0] = *(const short8*)(aptr + ((lp * 8 + wv * 2 + 0) * 16 + kp) * 512);
                af[gp & 1][1] = *(const short8*)(aptr + ((lp * 8 + wv * 2 + 1) * 16 + kp) * 512);
            }
            if (kb < 15) {   // prefetch next step's B from LDS (k-chunk ck=(kb+1)*2+h5)
                const int off = ((((kb + 1) * 2 + h5) ^ l31) << 3);
#pragma unroll
                for (int tj = 0; tj < 4; ++tj)
                    bfr[(kb + 1) & 1][tj] = *(const short8*)(hbuf + jb[tj] + off);
            }
#pragma unroll
            for (int tn = 0; tn < 2; ++tn)
#pragma unroll
                for (int tj = 0; tj < 4; ++tj)
                    acc[tn][tj] = __builtin_amdgcn_mfma_f32_32x32x16_bf16(
                        af[g & 1][tn], bfr[kb & 1][tj], acc[tn][tj], 0, 0, 0);
        }
        lds_barrier();   // hbuf reads of layer l done; af prefetch stays in flight

        if (l < 2) {
            // writeback: quad q of tile (tn,tj): n_base = n0+tn*32+8q+4h5 (4 consecutive n),
            // j = tj*32 + l31; packed 8B into swizzled h layout.
#pragma unroll
            for (int tn = 0; tn < 2; ++tn)
#pragma unroll
                for (int q = 0; q < 4; ++q) {
                    const int nb_ = n0 + tn * 32 + 8 * q + 4 * h5;
                    const int cn = nb_ >> 3, sub = nb_ & 7;
#pragma unroll
                    for (int tj = 0; tj < 4; ++tj) {
                        const int j = tj * 32 + l31;
                        int addr = j * 256 + ((cn ^ l31) << 3) + sub;
                        *(uint2v*)(hbuf + addr) = (uint2v){
                            pack2(relu(acc[tn][tj][q * 4]), relu(acc[tn][tj][q * 4 + 1])),
                            pack2(relu(acc[tn][tj][q * 4 + 2]), relu(acc[tn][tj][q * 4 + 3]))};
                    }
                }
            lds_barrier();
            // bfr kb=0 of next layer
#pragma unroll
            for (int tj = 0; tj < 4; ++tj)
                bfr[0][tj] = *(const short8*)(hbuf + jb[tj] + ((h5 ^ l31) << 3));
        } else {
            // full mean over j=128 in-wave: sum 4 tj-tiles, reduce over 32 j-lanes
#pragma unroll
            for (int tn = 0; tn < 2; ++tn)
#pragma unroll
                for (int r = 0; r < 16; ++r) {
                    float s = acc[tn][0][r] + acc[tn][1][r] + acc[tn][2][r] + acc[tn][3][r];
                    s += __shfl_xor(s, 1);
                    s += __shfl_xor(s, 2);
                    s += __shfl_xor(s, 4);
                    s += __shfl_xor(s, 8);
                    s += __shfl_xor(s, 16);
                    if (l31 == 0) {
                        const int n = n0 + tn * 32 + (r & 3) + 8 * (r >> 2) + 4 * h5;
                        pooled[w * 256 + n] = s * 0.0078125f;
                    }
                }
        }
    }
}

// ---- decoder: 256 WGs x 4 rows.
__global__ void dec_kernel(const float* __restrict__ pooled,
                           const float* __restrict__ wd1, const float* __restrict__ bd1,
                           const float* __restrict__ wd2, const float* __restrict__ bd2,
                           float* __restrict__ out) {
    __shared__ float ps[4][256];
    __shared__ float t1[4][260];
    const int g = blockIdx.x, t = threadIdx.x;
#pragma unroll
    for (int r = 0; r < 4; ++r) ps[r][t] = pooled[(g * 4 + r) * 256 + t];
    __syncthreads();
    {
        float acc[4];
        float bv = bd1[t];
#pragma unroll
        for (int r = 0; r < 4; ++r) acc[r] = bv;
#pragma unroll 16
        for (int k = 0; k < 256; ++k) {
            float wv = wd1[k * 256 + t];
#pragma unroll
            for (int r = 0; r < 4; ++r) acc[r] += ps[r][k] * wv;
        }
#pragma unroll
        for (int r = 0; r < 4; ++r) t1[r][t] = relu(acc[r]);
    }
    __syncthreads();
    {
        const int o = t & 63, rr = t >> 6;
        float a = 0.f;
#pragma unroll 16
        for (int k = 0; k < 256; ++k) a += t1[rr][k] * wd2[k * 64 + o];
        out[(g * 4 + rr) * 64 + o] = a + bd2[o];
    }
}

extern "C" void kernel_launch(void* const* d_in, const int* in_sizes, int n_in,
                              void* d_out, int out_size, void* d_ws, size_t ws_size,
                              hipStream_t stream) {
    const float* x0    = (const float*)d_in[0];
    const float* x1    = (const float*)d_in[1];
    const float* x2    = (const float*)d_in[2];
    const float* w_enc = (const float*)d_in[3];
    const float* b_enc = (const float*)d_in[4];
    const float* w1    = (const float*)d_in[5];
    const float* b1    = (const float*)d_in[6];
    const float* w2    = (const float*)d_in[7];
    const float* b2    = (const float*)d_in[8];
    const float* w3    = (const float*)d_in[9];
    const float* b3    = (const float*)d_in[10];
    const float* wd1   = (const float*)d_in[11];
    const float* bd1   = (const float*)d_in[12];
    const float* wd2   = (const float*)d_in[13];
    const float* bd2   = (const float*)d_in[14];
    float* out = (float*)d_out;

    // workspace: wfrag (384KB) | ea (1MB) | eb (1MB) | pooled (1MB)
    unsigned short* wt = (unsigned short*)d_ws;
    float* ea     = (float*)((char*)d_ws + 3 * 65536 * sizeof(unsigned short));
    float* eb     = ea + NROW * HID;
    float* pooled = eb + NROW * HID;

    setup_kernel<<<536, 256, 0, stream>>>(x0, x1, x2, w_enc, b_enc, w1, w2, w3, wt, ea, eb);
    pair_kernel<<<NROW, 256, 0, stream>>>(ea, eb, wt, b1, b2, b3, pooled);
    dec_kernel<<<256, 256, 0, stream>>>(pooled, wd1, bd1, wd2, bd2, out);
}

// Round 13
// 169.659 us; speedup vs baseline: 1.4428x; 1.1388x over previous
//
#include <hip/hip_runtime.h>
#include <stdint.h>

// B=8, OBJ=128, INP=64, HID=256, D=192.
// R13: (1) af prefetch ring-4 (distance 3) so MFMA never waits on a load
// issued <3 steps ago (~400+ cyc coverage vs ~250 cyc L2 latency);
// (2) decoder fused into pair epilogue (pooled row is WG-local since R12) —
// dec kernel, its launch, and the pooled global round-trip eliminated.

#define HID 256
#define NOBJ 128
#define NROW 1024   // B*OBJ

typedef __attribute__((ext_vector_type(8))) short short8;
typedef __attribute__((ext_vector_type(4))) float float4v;
typedef __attribute__((ext_vector_type(16))) float float16v;
typedef __attribute__((ext_vector_type(2))) unsigned int uint2v;

__device__ __forceinline__ unsigned int f2bf_u(float f) {
    unsigned int u = __builtin_bit_cast(unsigned int, f);
    u += 0x7fffu + ((u >> 16) & 1u);   // RNE
    return u >> 16;
}
__device__ __forceinline__ unsigned int pack2(float a, float b) {
    return f2bf_u(a) | (f2bf_u(b) << 16);
}
__device__ __forceinline__ float relu(float v) { return v > 0.f ? v : 0.f; }

// LDS-only barrier: leaves global-load (vmcnt) prefetches in flight.
__device__ __forceinline__ void lds_barrier() {
    asm volatile("s_waitcnt lgkmcnt(0)\n\ts_barrier" ::: "memory");
}

// ---- setup: blocks [0,24) fragment-major weight pack: block = (layer m, n-tile tau).
//             blocks [24,536) encoder (2 rows each, fold b_enc into ea)
__global__ void setup_kernel(const float* __restrict__ x0, const float* __restrict__ x1,
                             const float* __restrict__ x2, const float* __restrict__ w_enc,
                             const float* __restrict__ b_enc,
                             const float* __restrict__ w1, const float* __restrict__ w2,
                             const float* __restrict__ w3,
                             unsigned short* __restrict__ wt,
                             float* __restrict__ ea, float* __restrict__ eb) {
    const int bx = blockIdx.x, t = threadIdx.x;
    __shared__ float lw[256][33];          // [k][n-within-tile]
    __shared__ float xs[2][192];
    if (bx < 24) {
        const int m = bx >> 3, tau = bx & 7;
        const float* w = (m == 0) ? w1 : (m == 1) ? w2 : w3;
        const int n = t & 31, kk = t >> 5;     // 8 k-rows per pass
#pragma unroll
        for (int rep = 0; rep < 32; ++rep) {
            int k = rep * 8 + kk;
            lw[k][n] = w[k * 256 + tau * 32 + n];   // coalesced 128B segments
        }
        __syncthreads();
        // pack: each (kb, lane) exactly once. lane = t&63, wave wq owns kb = wq*4..+3.
        unsigned short* outp = wt + (m * 8 + tau) * 8192;
        const int lane = t & 63, wq = t >> 6;
        const int h5 = lane >> 5, l31n = lane & 31;
#pragma unroll
        for (int rep = 0; rep < 4; ++rep) {
            const int kb = wq * 4 + rep;
            short8 v;
#pragma unroll
            for (int e = 0; e < 8; ++e)
                v[e] = (short)f2bf_u(lw[kb * 16 + h5 * 8 + e][l31n]);
            *(short8*)(outp + kb * 512 + lane * 8) = v;   // wave-contiguous 1KB
        }
        return;
    }
    const int e = bx - 24;                 // 512 groups x 2 rows
    for (int idx = t; idx < 384; idx += 256) {
        int r = idx / 192, d = idx % 192;
        int row = e * 2 + r;
        float v = (d < 64) ? x0[row * 64 + d]
                : (d < 128) ? x1[row * 64 + d - 64]
                : x2[row * 64 + d - 128];
        xs[r][d] = v;
    }
    __syncthreads();
    float aA[2] = {0.f, 0.f}, aB[2] = {0.f, 0.f};
#pragma unroll 16
    for (int d = 0; d < 192; ++d) {
        float wa = w_enc[d * 256 + t];
        float wb = w_enc[(192 + d) * 256 + t];
#pragma unroll
        for (int r = 0; r < 2; ++r) { aA[r] += xs[r][d] * wa; aB[r] += xs[r][d] * wb; }
    }
    float be = b_enc[t];
#pragma unroll
    for (int r = 0; r < 2; ++r) {
        ea[(e * 2 + r) * 256 + t] = aA[r] + be;
        eb[(e * 2 + r) * 256 + t] = aB[r];
    }
}

// ---- pair MLP + fused decoder: grid 1024, one WG per (b,i). 128 j-rows,
//      64 KB LDS h, swizzle: elem(j,k) at j*256 + ((k>>3 ^ (j&31))<<3) + (k&7).
//      Wave wv owns n-quarter n0 = wv*64 as tn=2 x tj=4 tiles of 32x32x16.
//      af = ring-4 (prefetch distance 3).
__global__ __launch_bounds__(256, 2) void pair_kernel(
        const float* __restrict__ ea, const float* __restrict__ eb,
        const unsigned short* __restrict__ wt,
        const float* __restrict__ b1, const float* __restrict__ b2,
        const float* __restrict__ b3,
        const float* __restrict__ wd1, const float* __restrict__ bd1,
        const float* __restrict__ wd2, const float* __restrict__ bd2,
        float* __restrict__ out) {
    __shared__ __align__(16) unsigned short hbuf[128 * 256];   // 64 KB

    const int w = blockIdx.x, b = w >> 7;
    const int t = threadIdx.x, wv = t >> 6, lane = t & 63;
    const int l31 = lane & 31, h5 = lane >> 5;
    const int n0 = wv * 64;

    const unsigned short* aptr = wt + lane * 8;   // + ((l*8 + wv*2+tn)*16 + kb)*512

    short8 af[4][2], bfr[2][4];
    // flat A-pipeline: preload g=0,1,2 (layer 0, kb 0..2) before the preamble
#pragma unroll
    for (int pg = 0; pg < 3; ++pg) {
        af[pg][0] = *(const short8*)(aptr + ((wv * 2 + 0) * 16 + pg) * 512);
        af[pg][1] = *(const short8*)(aptr + ((wv * 2 + 1) * 16 + pg) * 512);
    }

    // preamble: h0[j][k] = relu(ea[w][k] + eb[b*128+j][k]); wave fills j=wv*32..+31
    {
        const float4v va = *(const float4v*)(ea + w * 256 + lane * 4);
        const float* ebbase = eb + (b * NOBJ) * 256;
        const int c = lane >> 1, sub = (lane & 1) * 4;
#pragma unroll 4
        for (int jj = 0; jj < 32; ++jj) {
            const int j = wv * 32 + jj;
            float4v vb = *(const float4v*)(ebbase + j * 256 + lane * 4);
            int addr = j * 256 + ((c ^ (j & 31)) << 3) + sub;
            *(uint2v*)(hbuf + addr) = (uint2v){
                pack2(relu(va[0] + vb[0]), relu(va[1] + vb[1])),
                pack2(relu(va[2] + vb[2]), relu(va[3] + vb[3]))};
        }
    }
    lds_barrier();

    int jb[4];
#pragma unroll
    for (int tj = 0; tj < 4; ++tj) jb[tj] = (tj * 32 + l31) * 256;
    // bfr kb=0 of layer 0: k-chunk ck = h5
#pragma unroll
    for (int tj = 0; tj < 4; ++tj)
        bfr[0][tj] = *(const short8*)(hbuf + jb[tj] + ((h5 ^ l31) << 3));

    float16v acc[2][4];   // [tn][tj]

#pragma unroll
    for (int l = 0; l < 3; ++l) {
        const float* bias = (l == 0) ? b1 : (l == 1) ? b2 : b3;
        // acc init: reg r of tile tn -> n = n0+tn*32 + (r&3)+8*(r>>2)+4*h5
#pragma unroll
        for (int tn = 0; tn < 2; ++tn)
#pragma unroll
            for (int q = 0; q < 4; ++q) {
                float4v bv = *(const float4v*)(bias + n0 + tn * 32 + q * 8 + h5 * 4);
#pragma unroll
                for (int i = 0; i < 4; ++i)
#pragma unroll
                    for (int tj = 0; tj < 4; ++tj)
                        acc[tn][tj][q * 4 + i] = bv[i];
            }
#pragma unroll
        for (int kb = 0; kb < 16; ++kb) {
            const int g = l * 16 + kb, gp = g + 3;
            if (gp < 48) {   // prefetch 3 steps ahead (crosses layer boundaries)
                const int lp = gp >> 4, kp = gp & 15;
                af[gp & 3][0] = *(const short8*)(aptr + ((lp * 8 + wv * 2 + 0) * 16 + kp) * 512);
                af[gp & 3][1] = *(const short8*)(aptr + ((lp * 8 + wv * 2 + 1) * 16 + kp) * 512);
            }
            if (kb < 15) {   // prefetch next step's B from LDS (k-chunk ck=(kb+1)*2+h5)
                const int off = ((((kb + 1) * 2 + h5) ^ l31) << 3);
#pragma unroll
                for (int tj = 0; tj < 4; ++tj)
                    bfr[(kb + 1) & 1][tj] = *(const short8*)(hbuf + jb[tj] + off);
            }
#pragma unroll
            for (int tn = 0; tn < 2; ++tn)
#pragma unroll
                for (int tj = 0; tj < 4; ++tj)
                    acc[tn][tj] = __builtin_amdgcn_mfma_f32_32x32x16_bf16(
                        af[g & 3][tn], bfr[kb & 1][tj], acc[tn][tj], 0, 0, 0);
        }
        lds_barrier();   // hbuf reads of layer l done; af prefetch stays in flight

        if (l < 2) {
            // writeback: quad q of tile (tn,tj): n_base = n0+tn*32+8q+4h5 (4 consecutive n),
            // j = tj*32 + l31; packed 8B into swizzled h layout.
#pragma unroll
            for (int tn = 0; tn < 2; ++tn)
#pragma unroll
                for (int q = 0; q < 4; ++q) {
                    const int nb_ = n0 + tn * 32 + 8 * q + 4 * h5;
                    const int cn = nb_ >> 3, sub = nb_ & 7;
#pragma unroll
                    for (int tj = 0; tj < 4; ++tj) {
                        const int j = tj * 32 + l31;
                        int addr = j * 256 + ((cn ^ l31) << 3) + sub;
                        *(uint2v*)(hbuf + addr) = (uint2v){
                            pack2(relu(acc[tn][tj][q * 4]), relu(acc[tn][tj][q * 4 + 1])),
                            pack2(relu(acc[tn][tj][q * 4 + 2]), relu(acc[tn][tj][q * 4 + 3]))};
                    }
                }
            lds_barrier();
            // bfr kb=0 of next layer
#pragma unroll
            for (int tj = 0; tj < 4; ++tj)
                bfr[0][tj] = *(const short8*)(hbuf + jb[tj] + ((h5 ^ l31) << 3));
        }
    }

    // ---- fused epilogue: pooled (mean_j + b3) -> LDS, then decoder GEMVs.
    float* fs = (float*)hbuf;   // pm[0..256) | t1[256..512) | partial[512..768)
    {
#pragma unroll
        for (int tn = 0; tn < 2; ++tn)
#pragma unroll
            for (int r = 0; r < 16; ++r) {
                float s = acc[tn][0][r] + acc[tn][1][r] + acc[tn][2][r] + acc[tn][3][r];
                s += __shfl_xor(s, 1);
                s += __shfl_xor(s, 2);
                s += __shfl_xor(s, 4);
                s += __shfl_xor(s, 8);
                s += __shfl_xor(s, 16);
                if (l31 == 0) {
                    const int n = n0 + tn * 32 + (r & 3) + 8 * (r >> 2) + 4 * h5;
                    fs[n] = s * 0.0078125f;
                }
            }
    }
    __syncthreads();
    // stage 1: t1[t] = relu(pm . wd1[:,t] + bd1[t])
    {
        float a1 = bd1[t];
#pragma unroll 16
        for (int k = 0; k < 256; ++k) a1 += fs[k] * wd1[k * 256 + t];
        __syncthreads();              // pm reads done before t1 writes reuse timing
        fs[256 + t] = relu(a1);
    }
    __syncthreads();
    // stage 2: wave wv handles k in [wv*64, wv*64+64); lane = output o
    {
        const int o = lane;
        float p = 0.f;
        const float* w2p = wd2 + (wv * 64) * 64 + o;
#pragma unroll 16
        for (int kk = 0; kk < 64; ++kk) p += fs[256 + wv * 64 + kk] * w2p[kk * 64];
        fs[512 + wv * 64 + o] = p;
    }
    __syncthreads();
    if (t < 64)
        out[w * 64 + t] = fs[512 + t] + fs[576 + t] + fs[640 + t] + fs[704 + t] + bd2[t];
}

extern "C" void kernel_launch(void* const* d_in, const int* in_sizes, int n_in,
                              void* d_out, int out_size, void* d_ws, size_t ws_size,
                              hipStream_t stream) {
    const float* x0    = (const float*)d_in[0];
    const float* x1    = (const float*)d_in[1];
    const float* x2    = (const float*)d_in[2];
    const float* w_enc = (const float*)d_in[3];
    const float* b_enc = (const float*)d_in[4];
    const float* w1    = (const float*)d_in[5];
    const float* b1    = (const float*)d_in[6];
    const float* w2    = (const float*)d_in[7];
    const float* b2    = (const float*)d_in[8];
    const float* w3    = (const float*)d_in[9];
    const float* b3    = (const float*)d_in[10];
    const float* wd1   = (const float*)d_in[11];
    const float* bd1   = (const float*)d_in[12];
    const float* wd2   = (const float*)d_in[13];
    const float* bd2   = (const float*)d_in[14];
    float* out = (float*)d_out;

    // workspace: wfrag (384KB) | ea (1MB) | eb (1MB)
    unsigned short* wt = (unsigned short*)d_ws;
    float* ea = (float*)((char*)d_ws + 3 * 65536 * sizeof(unsigned short));
    float* eb = ea + NROW * HID;

    setup_kernel<<<536, 256, 0, stream>>>(x0, x1, x2, w_enc, b_enc, w1, w2, w3, wt, ea, eb);
    pair_kernel<<<NROW, 256, 0, stream>>>(ea, eb, wt, b1, b2, b3,
                                          wd1, bd1, wd2, bd2, out);
}